// Round 6
// baseline (508.398 us; speedup 1.0000x reference)
//
#include <hip/hip_runtime.h>
#include <hip/hip_cooperative_groups.h>
#include <math.h>

#define MM 4096
#define DD 2048
#define DEN_BASE 8192       // ws float-offset of per-block denom partials (32-float = 128 B stride)

namespace cg = cooperative_groups;

// Agent(device)-scope coherent load: sc-bits bypass the (possibly stale) local L2.
__device__ __forceinline__ float aload(const float* p)
{
    return __hip_atomic_load(p, __ATOMIC_RELAXED, __HIP_MEMORY_SCOPE_AGENT);
}

// ============================ FUSED (cooperative) ============================
// ws handoff: [0..M) qt, [M..2M) k(scaled); [DEN_BASE + 32*b] per-block n.q partial.
// Everything else (it/ft/ot, v, n, ht numerators) stays block-local.
// Round-4 failure model: grid.sync release writes back dirty bytes but leaves
// resident L2 lines with stale bytes for OTHER XCDs' writes (n passed = self reads,
// C failed = cross reads). Fix: reader-side __threadfence (buffer_inv) + agent-scope
// loads for all cross-block data.
__global__ __launch_bounds__(256, 4) void fused(
    const float* __restrict__ x,  const float* __restrict__ cp,
    const float* __restrict__ n_prev,
    const float* __restrict__ Wq, const float* __restrict__ bq,
    const float* __restrict__ Wk, const float* __restrict__ bk,
    const float* __restrict__ Wv, const float* __restrict__ bV,
    const float* __restrict__ Wi, const float* __restrict__ bi,
    const float* __restrict__ Wf, const float* __restrict__ bf,
    const float* __restrict__ Wo, const float* __restrict__ bo,
    float* __restrict__ ws, float* __restrict__ ht,
    float* __restrict__ C_out, float* __restrict__ n_out)
{
    cg::grid_group grid = cg::this_grid();
    const int tid  = threadIdx.x;
    const int lane = tid & 63;
    const int wid  = tid >> 6;
    const int b    = blockIdx.x;

    __shared__ float xs[DD];        // 8 KB
    __shared__ float gates[3];      // it, ft, ot (block-local, recomputed per block)
    __shared__ float vloc[4];       // v for this block's 4 rows
    __shared__ float dred[4];
    __shared__ float dsr[4];
    __shared__ float sred[4];

    {   // stage x
        const float4* xv  = (const float4*)x;
        float4*       xsv = (float4*)xs;
        xsv[tid]       = xv[tid];
        xsv[256 + tid] = xv[256 + tid];
    }
    __syncthreads();

    const float4* xs4 = (const float4*)xs;

    // ---- gates: waves 0..2 compute i/f/o REDUNDANTLY per block (8 KB each, L2-hit) ----
    if (wid < 3) {
        const float* G = (wid == 0) ? Wi : ((wid == 1) ? Wf : Wo);
        const float4* g4 = (const float4*)G;
        double acc = 0.0;
        #pragma unroll
        for (int t = 0; t < 8; ++t) {
            float4 gg = g4[t * 64 + lane], xx = xs4[t * 64 + lane];
            acc += (double)gg.x * xx.x + (double)gg.y * xx.y
                 + (double)gg.z * xx.z + (double)gg.w * xx.w;
        }
        for (int off = 32; off; off >>= 1) acc += __shfl_down(acc, off, 64);
        if (lane == 0) {
            if (wid == 0)      gates[0] = (float)exp(acc + (double)bi[0]);
            else if (wid == 1) gates[1] = (float)exp(acc + (double)bf[0]);
            else               gates[2] = (float)(1.0 / (1.0 + exp(-(acc + (double)bo[0]))));
        }
    }

    // ---- row triple: wave w -> row 4b+w (q,k,v dots) ----
    const int row = b * 4 + wid;
    float aq = 0.f, ak = 0.f, av = 0.f;
    {
        const float4* q4 = (const float4*)(Wq + (size_t)row * DD);
        const float4* k4 = (const float4*)(Wk + (size_t)row * DD);
        const float4* v4 = (const float4*)(Wv + (size_t)row * DD);
        #pragma unroll
        for (int t = 0; t < 8; ++t) {
            float4 xx = xs4[t * 64 + lane];
            float4 qq = q4[t * 64 + lane];
            float4 kk = k4[t * 64 + lane];
            float4 vv = v4[t * 64 + lane];
            aq += qq.x * xx.x + qq.y * xx.y + qq.z * xx.z + qq.w * xx.w;
            ak += kk.x * xx.x + kk.y * xx.y + kk.z * xx.z + kk.w * xx.w;
            av += vv.x * xx.x + vv.y * xx.y + vv.z * xx.z + vv.w * xx.w;
        }
        for (int off = 32; off; off >>= 1) {
            aq += __shfl_down(aq, off, 64);
            ak += __shfl_down(ak, off, 64);
            av += __shfl_down(av, off, 64);
        }
    }
    __syncthreads();                 // gates[] ready

    if (lane == 0) {
        const float it = gates[0], ft = gates[1];
        const float qt = aq + bq[row];
        const float kk = (ak + bk[row]) * (1.0f / 64.0f);   // 1/sqrt(4096)
        const float vv = av + bV[row];
        ws[row]      = qt;
        ws[MM + row] = kk;
        vloc[wid]    = vv;
        const float nr = fmaf(ft, n_prev[row], it * kk);
        n_out[row]   = nr;                                   // self data: always coherent
        dred[wid]    = nr * qt;
    }
    __syncthreads();
    if (tid == 0)
        ws[DEN_BASE + 32 * b] = dred[0] + dred[1] + dred[2] + dred[3];  // 128B-exclusive slot

    __threadfence();      // release: write back our ws bytes to the coherent point
    grid.sync();
    __threadfence();      // acquire: INVALIDATE local L1/L2 (the bit round 4 was missing)

    // ---------------- phase 2: this block's 4 C rows + ht ----------------
    const float it = gates[0], ft = gates[1], ot = gates[2];

    // denom = | sum of 1024 per-block partials |  (agent-coherent loads, deterministic)
    float dsum = 0.f;
    #pragma unroll
    for (int u = 0; u < 4; ++u)
        dsum += aload(ws + DEN_BASE + 32 * (tid + 256 * u));
    for (int off = 32; off; off >>= 1) dsum += __shfl_down(dsum, off, 64);
    if (lane == 0) dsr[wid] = dsum;
    __syncthreads();
    const float denom = fmaxf(fabsf(dsr[0] + dsr[1] + dsr[2] + dsr[3]), 1.0f);

    // gather full qt/k vectors via agent-coherent scalar loads (fresh cross-XCD)
    float kkv[16], qqv[16];
    #pragma unroll
    for (int u = 0; u < 4; ++u) {
        const int base = 4 * (tid + 256 * u);
        #pragma unroll
        for (int e = 0; e < 4; ++e) {
            kkv[4 * u + e] = aload(ws + MM + base + e);
            qqv[4 * u + e] = aload(ws + base + e);
        }
    }

    for (int j = 0; j < 4; ++j) {
        const int r = b * 4 + j;
        const float ivi = it * vloc[j];
        const float4* cprow = (const float4*)(cp + (size_t)r * MM);
        float4*       crow  = (float4*)(C_out + (size_t)r * MM);
        float acc = 0.f;
        #pragma unroll
        for (int u = 0; u < 4; ++u) {
            float4 c = cprow[tid + 256 * u];
            float4 o;
            o.x = fmaf(ivi, kkv[4 * u + 0], ft * c.x);
            o.y = fmaf(ivi, kkv[4 * u + 1], ft * c.y);
            o.z = fmaf(ivi, kkv[4 * u + 2], ft * c.z);
            o.w = fmaf(ivi, kkv[4 * u + 3], ft * c.w);
            crow[tid + 256 * u] = o;
            acc += o.x * qqv[4 * u + 0] + o.y * qqv[4 * u + 1]
                 + o.z * qqv[4 * u + 2] + o.w * qqv[4 * u + 3];
        }
        for (int off = 32; off; off >>= 1) acc += __shfl_down(acc, off, 64);
        if (lane == 0) sred[wid] = acc;
        __syncthreads();
        if (tid == 0) ht[r] = ot * ((sred[0] + sred[1] + sred[2] + sred[3]) / denom);
        __syncthreads();
    }
}

// ============================ FALLBACK (proven 3-kernel, round-5 exact) ============================
__global__ __launch_bounds__(256, 4) void k1_gemv_gates(
    const float* __restrict__ x,
    const float* __restrict__ Wq, const float* __restrict__ bq,
    const float* __restrict__ Wk, const float* __restrict__ bk,
    const float* __restrict__ Wv, const float* __restrict__ bV,
    const float* __restrict__ Wi, const float* __restrict__ bi,
    const float* __restrict__ Wf, const float* __restrict__ bf,
    const float* __restrict__ Wo, const float* __restrict__ bo,
    float* __restrict__ ws)
{
    const int lane = threadIdx.x & 63;
    const int wid  = threadIdx.x >> 6;

    if (blockIdx.x >= 3072) {
        __shared__ double gred[4];
        const int g = blockIdx.x - 3072;
        const float* G = (g == 0) ? Wi : ((g == 1) ? Wf : Wo);
        const float4* g4 = (const float4*)G;
        const float4* xv = (const float4*)x;
        double acc = 0.0;
        for (int t = threadIdx.x; t < DD / 4; t += 256) {
            float4 gg = g4[t];
            float4 xx = xv[t];
            acc += (double)gg.x * xx.x + (double)gg.y * xx.y
                 + (double)gg.z * xx.z + (double)gg.w * xx.w;
        }
        for (int off = 32; off; off >>= 1) acc += __shfl_down(acc, off, 64);
        if (lane == 0) gred[wid] = acc;
        __syncthreads();
        if (threadIdx.x == 0) {
            double s = gred[0] + gred[1] + gred[2] + gred[3];
            if (g == 0)      ws[3 * MM + 0] = (float)exp(s + (double)bi[0]);
            else if (g == 1) ws[3 * MM + 1] = (float)exp(s + (double)bf[0]);
            else             ws[3 * MM + 2] = (float)(1.0 / (1.0 + exp(-(s + (double)bo[0]))));
        }
        return;
    }

    __shared__ float xs[DD];
    {
        const float4* xv  = (const float4*)x;
        float4*       xsv = (float4*)xs;
        xsv[threadIdx.x]       = xv[threadIdx.x];
        xsv[256 + threadIdx.x] = xv[256 + threadIdx.x];
    }
    __syncthreads();

    const int m   = blockIdx.x >> 10;
    const int row = ((blockIdx.x & 1023) << 2) + wid;

    const float* W = (m == 0) ? Wq : ((m == 1) ? Wk : Wv);
    const float4* w4  = (const float4*)(W + (size_t)row * DD);
    const float4* xs4 = (const float4*)xs;

    float acc = 0.f;
    #pragma unroll
    for (int t = 0; t < 8; ++t) {
        float4 ww = w4 [t * 64 + lane];
        float4 xx = xs4[t * 64 + lane];
        acc += ww.x * xx.x + ww.y * xx.y + ww.z * xx.z + ww.w * xx.w;
    }
    for (int off = 32; off; off >>= 1) acc += __shfl_down(acc, off, 64);

    if (lane == 0) {
        if (m == 0)      ws[row]          = acc + bq[row];
        else if (m == 1) ws[MM + row]     = (acc + bk[row]) * (1.0f / 64.0f);
        else             ws[2 * MM + row] = acc + bV[row];
    }
}

__global__ __launch_bounds__(256) void k2_rowC(
    const float* __restrict__ cp, const float* __restrict__ n_prev,
    float* __restrict__ ws, float* __restrict__ C_out, float* __restrict__ n_out)
{
    const int lane = threadIdx.x & 63;
    const int wid  = threadIdx.x >> 6;

    if (blockIdx.x == MM) {
        __shared__ float pred[4];
        const float it = ws[3 * MM + 0];
        const float ft = ws[3 * MM + 1];
        const float4* np4 = (const float4*)n_prev;
        const float4* kv4 = (const float4*)(ws + MM);
        const float4* qv4 = (const float4*)ws;
        float4* n4 = (float4*)n_out;
        float acc = 0.f;
        #pragma unroll
        for (int u = 0; u < 4; ++u) {
            int t = threadIdx.x + 256 * u;
            float4 np = np4[t], kk = kv4[t], qq = qv4[t];
            float4 nn;
            nn.x = fmaf(ft, np.x, it * kk.x);
            nn.y = fmaf(ft, np.y, it * kk.y);
            nn.z = fmaf(ft, np.z, it * kk.z);
            nn.w = fmaf(ft, np.w, it * kk.w);
            n4[t] = nn;
            acc += nn.x * qq.x + nn.y * qq.y + nn.z * qq.z + nn.w * qq.w;
        }
        for (int off = 32; off; off >>= 1) acc += __shfl_down(acc, off, 64);
        if (lane == 0) pred[wid] = acc;
        __syncthreads();
        if (threadIdx.x == 0) {
            float s = pred[0] + pred[1] + pred[2] + pred[3];
            ws[3 * MM + 3] = fmaxf(fabsf(s), 1.0f);
        }
        return;
    }

    __shared__ float sred[4];
    const int row = blockIdx.x;
    const float it  = ws[3 * MM + 0];
    const float ft  = ws[3 * MM + 1];
    const float ivi = it * ws[2 * MM + row];

    const float4* cprow = (const float4*)(cp + (size_t)row * MM);
    const float4* kv4   = (const float4*)(ws + MM);
    const float4* qv4   = (const float4*)ws;
    float4*       crow  = (float4*)(C_out + (size_t)row * MM);

    float4 c[4], kk[4], qq[4];
    #pragma unroll
    for (int u = 0; u < 4; ++u) c[u]  = cprow[threadIdx.x + 256 * u];
    #pragma unroll
    for (int u = 0; u < 4; ++u) kk[u] = kv4[threadIdx.x + 256 * u];
    #pragma unroll
    for (int u = 0; u < 4; ++u) qq[u] = qv4[threadIdx.x + 256 * u];

    float acc = 0.f;
    #pragma unroll
    for (int u = 0; u < 4; ++u) {
        float4 o;
        o.x = fmaf(ivi, kk[u].x, ft * c[u].x);
        o.y = fmaf(ivi, kk[u].y, ft * c[u].y);
        o.z = fmaf(ivi, kk[u].z, ft * c[u].z);
        o.w = fmaf(ivi, kk[u].w, ft * c[u].w);
        crow[threadIdx.x + 256 * u] = o;
        acc += o.x * qq[u].x + o.y * qq[u].y + o.z * qq[u].z + o.w * qq[u].w;
    }
    for (int off = 32; off; off >>= 1) acc += __shfl_down(acc, off, 64);
    if (lane == 0) sred[wid] = acc;
    __syncthreads();
    if (threadIdx.x == 0)
        ws[4 * MM + row] = sred[0] + sred[1] + sred[2] + sred[3];
}

__global__ __launch_bounds__(256) void k3_finalize(
    const float* __restrict__ ws, float* __restrict__ ht_out)
{
    const float ot    = ws[3 * MM + 2];
    const float denom = ws[3 * MM + 3];
    const int i = blockIdx.x * 256 + threadIdx.x;
    ht_out[i] = ot * (ws[4 * MM + i] / denom);
}

extern "C" void kernel_launch(void* const* d_in, const int* in_sizes, int n_in,
                              void* d_out, int out_size, void* d_ws, size_t ws_size,
                              hipStream_t stream)
{
    const float* x      = (const float*)d_in[0];
    const float* cp     = (const float*)d_in[1];
    const float* n_prev = (const float*)d_in[2];
    const float* Wq = (const float*)d_in[3];
    const float* bq = (const float*)d_in[4];
    const float* Wk = (const float*)d_in[5];
    const float* bk = (const float*)d_in[6];
    const float* Wv = (const float*)d_in[7];
    const float* bV = (const float*)d_in[8];
    const float* Wi = (const float*)d_in[9];
    const float* bi = (const float*)d_in[10];
    const float* Wf = (const float*)d_in[11];
    const float* bf = (const float*)d_in[12];
    const float* Wo = (const float*)d_in[13];
    const float* bo = (const float*)d_in[14];

    float* out = (float*)d_out;
    float* ht  = out;                        // (M,1)
    float* C   = out + MM;                   // (M,M)
    float* n   = out + MM + (size_t)MM * MM; // (M,1)
    float* ws  = (float*)d_ws;

    void* args[] = {
        (void*)&x, (void*)&cp, (void*)&n_prev,
        (void*)&Wq, (void*)&bq, (void*)&Wk, (void*)&bk, (void*)&Wv, (void*)&bV,
        (void*)&Wi, (void*)&bi, (void*)&Wf, (void*)&bf, (void*)&Wo, (void*)&bo,
        (void*)&ws, (void*)&ht, (void*)&C, (void*)&n
    };
    hipError_t err = hipLaunchCooperativeKernel((const void*)fused, dim3(1024),
                                                dim3(256), args, 0, stream);
    if (err != hipSuccess) {
        // proven 3-kernel path (round-5 exact): zero-regression fallback
        k1_gemv_gates<<<3075, 256, 0, stream>>>(x, Wq, bq, Wk, bk, Wv, bV,
                                                Wi, bi, Wf, bf, Wo, bo, ws);
        k2_rowC      <<<MM + 1, 256, 0, stream>>>(cp, n_prev, ws, C, n);
        k3_finalize  <<<MM / 256, 256, 0, stream>>>(ws, ht);
    }
}

// Round 7
// 222.446 us; speedup vs baseline: 2.2855x; 2.2855x over previous
//
#include <hip/hip_runtime.h>
#include <math.h>

#define MM 4096
#define DD 2048

// ws layout (floats):
// [0..M)    qt
// [M..2M)   k (scaled by 1/sqrt(M))
// [2M..3M)  v
// [3M+0] it, [3M+1] ft, [3M+2] ot, [3M+3] denom
// [4M..5M)  num (per-row C@qt numerator)

// ---------------- K1: qt/k/v GEMVs; ENFORCED 8-deep load clustering ----------------
// Round-5 lesson: compiler re-serialized preloads (VGPR stayed 36). sched_barrier(0)
// is a hard fence: all 8 W-loads must issue before any FMA -> 8 KB in flight per wave.
__global__ __launch_bounds__(256, 4) void k1_gemv_gates(
    const float* __restrict__ x,
    const float* __restrict__ Wq, const float* __restrict__ bq,
    const float* __restrict__ Wk, const float* __restrict__ bk,
    const float* __restrict__ Wv, const float* __restrict__ bV,
    const float* __restrict__ Wi, const float* __restrict__ bi,
    const float* __restrict__ Wf, const float* __restrict__ bf,
    const float* __restrict__ Wo, const float* __restrict__ bo,
    float* __restrict__ ws)
{
    const int lane = threadIdx.x & 63;
    const int wid  = threadIdx.x >> 6;

    if (blockIdx.x >= 3072) {
        // ----- gate blocks: double-precision dot over D -----
        __shared__ double gred[4];
        const int g = blockIdx.x - 3072;           // 0=i, 1=f, 2=o
        const float* G = (g == 0) ? Wi : ((g == 1) ? Wf : Wo);
        const float4* g4 = (const float4*)G;
        const float4* xv = (const float4*)x;
        double acc = 0.0;
        for (int t = threadIdx.x; t < DD / 4; t += 256) {
            float4 gg = g4[t];
            float4 xx = xv[t];
            acc += (double)gg.x * xx.x + (double)gg.y * xx.y
                 + (double)gg.z * xx.z + (double)gg.w * xx.w;
        }
        for (int off = 32; off; off >>= 1) acc += __shfl_down(acc, off, 64);
        if (lane == 0) gred[wid] = acc;
        __syncthreads();
        if (threadIdx.x == 0) {
            double s = gred[0] + gred[1] + gred[2] + gred[3];
            if (g == 0)      ws[3 * MM + 0] = (float)exp(s + (double)bi[0]);
            else if (g == 1) ws[3 * MM + 1] = (float)exp(s + (double)bf[0]);
            else             ws[3 * MM + 2] = (float)(1.0 / (1.0 + exp(-(s + (double)bo[0]))));
        }
        return;
    }

    // ----- row blocks: 4 waves, one (matrix,row) dot per wave -----
    __shared__ float xs[DD];                 // 8 KB

    {   // stage x once
        const float4* xv  = (const float4*)x;
        float4*       xsv = (float4*)xs;
        xsv[threadIdx.x]       = xv[threadIdx.x];
        xsv[256 + threadIdx.x] = xv[256 + threadIdx.x];
    }
    __syncthreads();

    const int m   = blockIdx.x >> 10;                  // 0=q, 1=k, 2=v
    const int row = ((blockIdx.x & 1023) << 2) + wid;

    const float* W = (m == 0) ? Wq : ((m == 1) ? Wk : Wv);
    const float4* w4  = (const float4*)(W + (size_t)row * DD);
    const float4* xs4 = (const float4*)xs;

    // --- issue ALL 8 global loads (whole row, 128 B/lane) before any use ---
    float4 wv[8];
    #pragma unroll
    for (int t = 0; t < 8; ++t) wv[t] = w4[t * 64 + lane];
    __builtin_amdgcn_sched_barrier(0);       // loads may not sink past this point
    // --- LDS reads of x (cheap latency, overlaps vmcnt drain) ---
    float4 xv_[8];
    #pragma unroll
    for (int t = 0; t < 8; ++t) xv_[t] = xs4[t * 64 + lane];
    __builtin_amdgcn_sched_barrier(0);

    float acc = 0.f;
    #pragma unroll
    for (int t = 0; t < 8; ++t)
        acc += wv[t].x * xv_[t].x + wv[t].y * xv_[t].y
             + wv[t].z * xv_[t].z + wv[t].w * xv_[t].w;

    for (int off = 32; off; off >>= 1) acc += __shfl_down(acc, off, 64);

    if (lane == 0) {
        if (m == 0)      ws[row]          = acc + bq[row];
        else if (m == 1) ws[MM + row]     = (acc + bk[row]) * (1.0f / 64.0f); // 1/sqrt(4096)
        else             ws[2 * MM + row] = acc + bV[row];
    }
}

// ---------------- K2: one row per block; 12-deep enforced cluster; plain stores ----------------
__global__ __launch_bounds__(256, 4) void k2_rowC(
    const float* __restrict__ cp, const float* __restrict__ n_prev,
    float* __restrict__ ws, float* __restrict__ C_out, float* __restrict__ n_out)
{
    const int lane = threadIdx.x & 63;
    const int wid  = threadIdx.x >> 6;

    if (blockIdx.x == MM) {
        // ----- n & denom block -----
        __shared__ float pred[4];
        const float it = ws[3 * MM + 0];
        const float ft = ws[3 * MM + 1];
        const float4* np4 = (const float4*)n_prev;
        const float4* kv4 = (const float4*)(ws + MM);
        const float4* qv4 = (const float4*)ws;
        float4* n4 = (float4*)n_out;
        float acc = 0.f;
        #pragma unroll
        for (int u = 0; u < 4; ++u) {
            int t = threadIdx.x + 256 * u;
            float4 np = np4[t], kk = kv4[t], qq = qv4[t];
            float4 nn;
            nn.x = fmaf(ft, np.x, it * kk.x);
            nn.y = fmaf(ft, np.y, it * kk.y);
            nn.z = fmaf(ft, np.z, it * kk.z);
            nn.w = fmaf(ft, np.w, it * kk.w);
            n4[t] = nn;
            acc += nn.x * qq.x + nn.y * qq.y + nn.z * qq.z + nn.w * qq.w;
        }
        for (int off = 32; off; off >>= 1) acc += __shfl_down(acc, off, 64);
        if (lane == 0) pred[wid] = acc;
        __syncthreads();
        if (threadIdx.x == 0) {
            float s = pred[0] + pred[1] + pred[2] + pred[3];
            ws[3 * MM + 3] = fmaxf(fabsf(s), 1.0f);
        }
        return;
    }

    __shared__ float sred[4];
    const int row = blockIdx.x;
    const float it  = ws[3 * MM + 0];
    const float ft  = ws[3 * MM + 1];
    const float ivi = it * ws[2 * MM + row];

    const float4* cprow = (const float4*)(cp + (size_t)row * MM);
    const float4* kv4   = (const float4*)(ws + MM);
    const float4* qv4   = (const float4*)ws;
    float4*       crow  = (float4*)(C_out + (size_t)row * MM);

    // --- cluster all 12 loads (4 HBM cp + 8 L2/L3 ws) before any use ---
    float4 c[4], kk[4], qq[4];
    #pragma unroll
    for (int u = 0; u < 4; ++u) c[u]  = cprow[threadIdx.x + 256 * u];
    #pragma unroll
    for (int u = 0; u < 4; ++u) kk[u] = kv4[threadIdx.x + 256 * u];
    #pragma unroll
    for (int u = 0; u < 4; ++u) qq[u] = qv4[threadIdx.x + 256 * u];
    __builtin_amdgcn_sched_barrier(0);

    float acc = 0.f;
    #pragma unroll
    for (int u = 0; u < 4; ++u) {
        float4 o;
        o.x = fmaf(ivi, kk[u].x, ft * c[u].x);
        o.y = fmaf(ivi, kk[u].y, ft * c[u].y);
        o.z = fmaf(ivi, kk[u].z, ft * c[u].z);
        o.w = fmaf(ivi, kk[u].w, ft * c[u].w);
        crow[threadIdx.x + 256 * u] = o;          // plain store (round-3 result)
        acc += o.x * qq[u].x + o.y * qq[u].y + o.z * qq[u].z + o.w * qq[u].w;
    }
    for (int off = 32; off; off >>= 1) acc += __shfl_down(acc, off, 64);
    if (lane == 0) sred[wid] = acc;
    __syncthreads();
    if (threadIdx.x == 0)
        ws[4 * MM + row] = sred[0] + sred[1] + sred[2] + sred[3];
}

// ---------------- K3: ht = ot * num / denom ----------------
__global__ __launch_bounds__(256) void k3_finalize(
    const float* __restrict__ ws, float* __restrict__ ht_out)
{
    const float ot    = ws[3 * MM + 2];
    const float denom = ws[3 * MM + 3];
    const int i = blockIdx.x * 256 + threadIdx.x;
    ht_out[i] = ot * (ws[4 * MM + i] / denom);
}

extern "C" void kernel_launch(void* const* d_in, const int* in_sizes, int n_in,
                              void* d_out, int out_size, void* d_ws, size_t ws_size,
                              hipStream_t stream)
{
    const float* x      = (const float*)d_in[0];
    const float* cp     = (const float*)d_in[1];
    const float* n_prev = (const float*)d_in[2];
    const float* Wq = (const float*)d_in[3];
    const float* bq = (const float*)d_in[4];
    const float* Wk = (const float*)d_in[5];
    const float* bk = (const float*)d_in[6];
    const float* Wv = (const float*)d_in[7];
    const float* bV = (const float*)d_in[8];
    const float* Wi = (const float*)d_in[9];
    const float* bi = (const float*)d_in[10];
    const float* Wf = (const float*)d_in[11];
    const float* bf = (const float*)d_in[12];
    const float* Wo = (const float*)d_in[13];
    const float* bo = (const float*)d_in[14];

    float* out = (float*)d_out;
    float* ht  = out;                        // (M,1)
    float* C   = out + MM;                   // (M,M)
    float* n   = out + MM + (size_t)MM * MM; // (M,1)
    float* ws  = (float*)d_ws;

    k1_gemv_gates<<<3075, 256, 0, stream>>>(x, Wq, bq, Wk, bk, Wv, bV,
                                            Wi, bi, Wf, bf, Wo, bo, ws);
    k2_rowC      <<<MM + 1, 256, 0, stream>>>(cp, n_prev, ws, C, n);
    k3_finalize  <<<MM / 256, 256, 0, stream>>>(ws, ht);
}